// Round 9
// baseline (325.023 us; speedup 1.0000x reference)
//
#include <hip/hip_runtime.h>
#include <hip/hip_bf16.h>

// Problem constants
#define NROWS   200000
#define TILE    64                  // rows (n) per block
#define NBLOCKS (NROWS / TILE)      // 3125, exact

typedef __attribute__((ext_vector_type(4))) float f32x4;
typedef __attribute__((ext_vector_type(8))) short bf16x8;

// fp32 pair -> packed bf16x2 (RNE), compiler-lowered packed convert
__device__ __forceinline__ unsigned pk2(float lo, float hi) {
  float2 f{lo, hi};
  __hip_bfloat162 h = __float22bfloat162_rn(f);
  unsigned u;
  __builtin_memcpy(&u, &h, 4);
  return u;
}
// single fp32 -> bf16 bits via packed cvt (low half); 1 instruction
__device__ __forceinline__ unsigned short bf1(float v) {
  return (unsigned short)pk2(v, v);
}
// scalar fp32 -> bf16 bits (RNE) — weight prep only (runs once)
__device__ __forceinline__ unsigned short f2bf(float f) {
  unsigned b = __float_as_uint(f);
  b += 0x7fffu + ((b >> 16) & 1u);
  return (unsigned short)(b >> 16);
}
__device__ __forceinline__ float bflo(unsigned pk) { return __uint_as_float(pk << 16); }
__device__ __forceinline__ float bfhi(unsigned pk) { return __uint_as_float(pk & 0xffff0000u); }
__device__ __forceinline__ f32x4 mfma16(bf16x8 a, bf16x8 b, f32x4 c) {
  return __builtin_amdgcn_mfma_f32_16x16x32_bf16(a, b, c, 0, 0, 0);
}
__device__ __forceinline__ float fast_tanh(float x) {
  float e = __expf(2.0f * x);
  return 1.0f - __fdividef(2.0f, e + 1.0f);
}
// LDS XOR swizzle on byte offsets (uniform 256B row pitch, row = byte>>8):
// flips bits 4..6 with row&7; pure function of the offset -> consistent;
// preserves 16B alignment; <=2-way bank aliasing on all access patterns here.
__device__ __forceinline__ int SW(int b) { return b ^ (((b >> 8) & 7) << 4); }

// ---------------------------------------------------------------------------
// Weight prep: W[K][Nout] fp32 -> bf16 MFMA-B fragments.
//   Wp: INTERLEAVED col mapping (col = (nt>>1)*32 + 2*lr + (nt&1)) — GEMM1
//       waves own tile PAIRS -> lane's 2 cols adjacent -> float2 out stores.
//   W1/W2: NATURAL mapping (col = nt*16 + lr) — MLP waves own single tiles
//       (8 waves x 1 tile = no duplicate loads; 256 KB/block exactly).
// Fragment (kt,nt) at index kt*NT+nt: lane l elem i <- W[kt*32+8*(l>>4)+i][col]
// ---------------------------------------------------------------------------
__global__ void prep_weights(const float* __restrict__ Wp,
                             const float* __restrict__ W1,
                             const float* __restrict__ W2,
                             unsigned short* __restrict__ wpf,
                             unsigned short* __restrict__ w1f,
                             unsigned short* __restrict__ w2f) {
  int t = blockIdx.x * 256 + threadIdx.x;   // 72*256 = 18432 = 288*64
  int q = t >> 6, l = t & 63;
  const float* W; unsigned short* dst; int NT, Nout, qb; bool inter;
  if (q < 32)       { W = Wp; dst = wpf; NT = 8;  Nout = 128; qb = q;       inter = true;  }
  else if (q < 160) { W = W1; dst = w1f; NT = 32; Nout = 512; qb = q - 32;  inter = false; }
  else              { W = W2; dst = w2f; NT = 8;  Nout = 128; qb = q - 160; inter = false; }
  int kt = qb / NT, nt = qb % NT;
  int row0 = kt * 32 + 8 * (l >> 4);
  int col  = inter ? (nt >> 1) * 32 + 2 * (l & 15) + (nt & 1)
                   : nt * 16 + (l & 15);
  unsigned short v[8];
#pragma unroll
  for (int i = 0; i < 8; ++i) v[i] = f2bf(W[(row0 + i) * Nout + col]);
  uint4 pack;
  pack.x = (unsigned)v[0] | ((unsigned)v[1] << 16);
  pack.y = (unsigned)v[2] | ((unsigned)v[3] << 16);
  pack.z = (unsigned)v[4] | ((unsigned)v[5] << 16);
  pack.w = (unsigned)v[6] | ((unsigned)v[7] << 16);
  *(uint4*)(dst + (size_t)(qb * 64 + l) * 8) = pack;
}

// ---------------------------------------------------------------------------
// Fused kernel (R9): TILE=64, 512 threads (8 waves) -> weight L2 traffic
// halves vs TILE=32 (288 KB x 3125 blocks = 0.9 GB). Per-wave split keeps
// register demand ~110 < 128 so launch_bounds(512,4) holds 2 blocks/CU
// (16 waves/CU) with LDS = 65536 B exactly.
// LDS map (256B row pitch, SW-swizzled):
//   [0,49152): x bf16 [192 rows'=3n+d][128]   (dead after GEMM1)
//     overlay: h1 buf0 @0 (16K) | h1 buf1 @16384 (16K) | h2 @32768 (16K)
//   [49152,65536): c bf16 [64][128]           (never overwritten)
// Wave roles: GEMM1/final: m-half h=w>>2 (6 m-tiles), col-pair p=w&3
//   (interleaved cols 32p+2*lr{,+1}).  MLP: single col-tile w, 4 m-tiles.
// Schedule: P0 | bar | GEMM1 | { gemm2(ch); [ch==0: bar]; epi->buf[ch&1];
//   bar; gemm3(ch) }x4 | h2 | bar | out.   7 barriers.
// ---------------------------------------------------------------------------
__global__ __launch_bounds__(512, 4) void fused_kernel(
    const float* __restrict__ x,
    const float* __restrict__ b1,
    const float* __restrict__ b2,
    const unsigned short* __restrict__ wpf,
    const unsigned short* __restrict__ w1f,
    const unsigned short* __restrict__ w2f,
    float* __restrict__ out) {
  __shared__ __align__(16) char smem[65536];
  const int t = threadIdx.x;   // 0..511
  const int l = t & 63;
  const int w = t >> 6;        // wave id 0..7
  const int lr = l & 15;
  const int lq = l >> 4;
  const int p = w & 3;         // col-pair (GEMM1/final)
  const int h = w >> 2;        // m-half  (GEMM1/final)
  const long n0 = (long)blockIdx.x * TILE;

  // ---- P0: stage x -> bf16 LDS; c = sum_d x^2 in fp32 from un-rounded x.
  // Thread t: row r = t>>3 (0..63), features f0..f0+15 (f0=(t&7)*16),
  // processed in two halves of 8 floats to cap transient regs.
  {
    const int r = t >> 3;
    const int f0 = (t & 7) * 16;
    const float* xp = x + (n0 + r) * 384 + f0;
#pragma unroll
    for (int hh = 0; hh < 2; ++hh) {
      float4 a0 = *(const float4*)(xp + hh * 8);
      float4 a1 = *(const float4*)(xp + hh * 8 + 4);
      float4 b0 = *(const float4*)(xp + 128 + hh * 8);
      float4 b1_ = *(const float4*)(xp + 132 + hh * 8);
      float4 c0 = *(const float4*)(xp + 256 + hh * 8);
      float4 c1 = *(const float4*)(xp + 260 + hh * 8);
      uint4 sa = { pk2(a0.x, a0.y), pk2(a0.z, a0.w), pk2(a1.x, a1.y), pk2(a1.z, a1.w) };
      uint4 sb = { pk2(b0.x, b0.y), pk2(b0.z, b0.w), pk2(b1_.x, b1_.y), pk2(b1_.z, b1_.w) };
      uint4 sc = { pk2(c0.x, c0.y), pk2(c0.z, c0.w), pk2(c1.x, c1.y), pk2(c1.z, c1.w) };
      uint4 cv = { pk2(a0.x*a0.x + b0.x*b0.x + c0.x*c0.x,
                       a0.y*a0.y + b0.y*b0.y + c0.y*c0.y),
                   pk2(a0.z*a0.z + b0.z*b0.z + c0.z*c0.z,
                       a0.w*a0.w + b0.w*b0.w + c0.w*c0.w),
                   pk2(a1.x*a1.x + b1_.x*b1_.x + c1.x*c1.x,
                       a1.y*a1.y + b1_.y*b1_.y + c1.y*c1.y),
                   pk2(a1.z*a1.z + b1_.z*b1_.z + c1.z*c1.z,
                       a1.w*a1.w + b1_.w*b1_.w + c1.w*c1.w) };
      const int fb = (f0 + hh * 8) * 2;
      *(uint4*)(smem + SW((3 * r + 0) * 256 + fb)) = sa;
      *(uint4*)(smem + SW((3 * r + 1) * 256 + fb)) = sb;
      *(uint4*)(smem + SW((3 * r + 2) * 256 + fb)) = sc;
      *(uint4*)(smem + SW(49152 + r * 256 + fb))   = cv;
    }
  }
  __syncthreads();   // (1) x + c visible

  // ---- GEMM1: linx[r'][g], 192x128. Wave: m-half h (6 m-tiles, two
  // sub-passes of 3), col-pair p (interleaved cols 32p+2*lr{,+1}).
  unsigned lx[6][4];
#pragma unroll
  for (int s = 0; s < 2; ++s) {
    f32x4 acc1[3][2] = {};
#pragma unroll
    for (int kt = 0; kt < 4; ++kt) {
      bf16x8 a[3];
#pragma unroll
      for (int m = 0; m < 3; ++m) {
        int row = h * 96 + (s * 3 + m) * 16 + lr;
        a[m] = *(const bf16x8*)(smem + SW(row * 256 + kt * 64 + lq * 16));
      }
#pragma unroll
      for (int jj = 0; jj < 2; ++jj) {
        bf16x8 b = *(const bf16x8*)(wpf + (size_t)((kt * 8 + 2 * p + jj) * 64 + l) * 8);
#pragma unroll
        for (int m = 0; m < 3; ++m) acc1[m][jj] = mfma16(a[m], b, acc1[m][jj]);
      }
    }
#pragma unroll
    for (int m = 0; m < 3; ++m)
#pragma unroll
      for (int reg = 0; reg < 4; ++reg)
        lx[s * 3 + m][reg] = pk2(acc1[m][0][reg], acc1[m][1][reg]);
  }

  // ---- MLP, K-chunked (128 mids/chunk), h1 dbuf @0/@16384.
  // Wave w owns single col-tile w (cols 16w+lr, natural order) x 4 m-tiles.
  f32x4 acc3[4] = {};
#pragma unroll
  for (int ch = 0; ch < 4; ++ch) {
    // gemm2(ch): reads stable c region + W1 frags only
    f32x4 acc2[4] = {};
#pragma unroll
    for (int kt = 0; kt < 4; ++kt) {
      bf16x8 b = *(const bf16x8*)(w1f + (size_t)((kt * 32 + ch * 8 + w) * 64 + l) * 8);
#pragma unroll
      for (int m = 0; m < 4; ++m) {
        bf16x8 a2 = *(const bf16x8*)(smem + SW(49152 + (m * 16 + lr) * 256 + kt * 64 + lq * 16));
        acc2[m] = mfma16(a2, b, acc2[m]);
      }
    }
    if (ch == 0) __syncthreads();   // (2) GEMM1's x reads done; buf0 writable
    // epilogue: bias + tanh -> b16 into buf[ch&1], col 16w+lr
    const int bufb = (ch & 1) * 16384;
    {
      float b1v = b1[ch * 128 + w * 16 + lr];
#pragma unroll
      for (int m = 0; m < 4; ++m)
#pragma unroll
        for (int reg = 0; reg < 4; ++reg) {
          int row = m * 16 + 4 * lq + reg;
          *(unsigned short*)(smem + SW(bufb + row * 256 + (w * 16 + lr) * 2)) =
              bf1(fast_tanh(acc2[m][reg] + b1v));
        }
    }
    __syncthreads();   // (3..6) h1 chunk visible
    // gemm3(ch): acc3 += h1c @ W2[K-slice, col-tile w]
#pragma unroll
    for (int kt = 0; kt < 4; ++kt) {
      bf16x8 b = *(const bf16x8*)(w2f + (size_t)(((ch * 4 + kt) * 8 + w) * 64 + l) * 8);
#pragma unroll
      for (int m = 0; m < 4; ++m) {
        bf16x8 a3 = *(const bf16x8*)(smem + SW(bufb + (m * 16 + lr) * 256 + kt * 64 + lq * 16));
        acc3[m] = mfma16(a3, b, acc3[m]);
      }
    }
  }

  // ---- h2 = acc3 + b2 -> bf16 @32768, col 16w+lr (natural)
  {
    float b2v = b2[w * 16 + lr];
#pragma unroll
    for (int m = 0; m < 4; ++m)
#pragma unroll
      for (int reg = 0; reg < 4; ++reg) {
        int row = m * 16 + 4 * lq + reg;
        *(unsigned short*)(smem + SW(32768 + row * 256 + (w * 16 + lr) * 2)) =
            bf1(acc3[m][reg] + b2v);
      }
  }
  __syncthreads();   // (7) h2 visible

  // ---- Final: out[n,d,g] = linx * h2 (paired cols 32p+2*lr -> b32 h2
  // reads + float2 stores). rp = h*96 + m*16 + 4*lq + reg, n = rp/3.
#pragma unroll
  for (int m = 0; m < 6; ++m)
#pragma unroll
    for (int reg = 0; reg < 4; ++reg) {
      int rp = h * 96 + m * 16 + 4 * lq + reg;
      int n = rp / 3;   // magic-mul
      unsigned hp = *(const unsigned*)(smem + SW(32768 + n * 256 + (p * 32 + 2 * lr) * 2));
      unsigned pk = lx[m][reg];
      float2 o = { bflo(pk) * bflo(hp), bfhi(pk) * bfhi(hp) };
      *(float2*)(out + n0 * 384 + (long)rp * 128 + p * 32 + 2 * lr) = o;
    }
}

extern "C" void kernel_launch(void* const* d_in, const int* in_sizes, int n_in,
                              void* d_out, int out_size, void* d_ws, size_t ws_size,
                              hipStream_t stream) {
  const float* x  = (const float*)d_in[0];
  const float* Wp = (const float*)d_in[1];
  const float* W1 = (const float*)d_in[2];
  const float* b1 = (const float*)d_in[3];
  const float* W2 = (const float*)d_in[4];
  const float* b2 = (const float*)d_in[5];
  float* out = (float*)d_out;

  // ws layout: W1f [128KB] | W2f [128KB] | Wpf [32KB]
  if (ws_size < 294912) return;
  unsigned short* w1f = (unsigned short*)d_ws;
  unsigned short* w2f = (unsigned short*)((char*)d_ws + 131072);
  unsigned short* wpf = (unsigned short*)((char*)d_ws + 262144);

  prep_weights<<<72, 256, 0, stream>>>(Wp, W1, W2, wpf, w1f, w2f);
  fused_kernel<<<NBLOCKS, 512, 0, stream>>>(x, b1, b2, wpf, w1f, w2f, out);
}

// Round 10
// 295.055 us; speedup vs baseline: 1.1016x; 1.1016x over previous
//
#include <hip/hip_runtime.h>
#include <hip/hip_bf16.h>

// Problem constants
#define NROWS   200000
#define TILE    32                  // rows (n) per block
#define NBLOCKS (NROWS / TILE)      // 6250, exact

typedef __attribute__((ext_vector_type(4))) float f32x4;
typedef __attribute__((ext_vector_type(8))) short bf16x8;

// fp32 pair -> packed bf16x2 (RNE), compiler-lowered packed convert
__device__ __forceinline__ unsigned pk2(float lo, float hi) {
  float2 f{lo, hi};
  __hip_bfloat162 h = __float22bfloat162_rn(f);
  unsigned u;
  __builtin_memcpy(&u, &h, 4);
  return u;
}
// scalar fp32 -> bf16 bits (RNE) — weight prep only (runs once)
__device__ __forceinline__ unsigned short f2bf(float f) {
  unsigned b = __float_as_uint(f);
  b += 0x7fffu + ((b >> 16) & 1u);
  return (unsigned short)(b >> 16);
}
__device__ __forceinline__ float bflo(unsigned pk) { return __uint_as_float(pk << 16); }
__device__ __forceinline__ float bfhi(unsigned pk) { return __uint_as_float(pk & 0xffff0000u); }
__device__ __forceinline__ f32x4 mfma16(bf16x8 a, bf16x8 b, f32x4 c) {
  return __builtin_amdgcn_mfma_f32_16x16x32_bf16(a, b, c, 0, 0, 0);
}
__device__ __forceinline__ float fast_tanh(float x) {
  float e = __expf(2.0f * x);
  return 1.0f - __fdividef(2.0f, e + 1.0f);
}
// LDS XOR swizzle on byte offsets (uniform 256B row pitch, row = byte>>8):
// flips bits 4..6 with row&7; pure function of the offset -> consistent;
// preserves 16B alignment; <=2-way bank aliasing on all access patterns here.
__device__ __forceinline__ int SW(int b) { return b ^ (((b >> 8) & 7) << 4); }

// ---------------------------------------------------------------------------
// Weight prep: W[K][Nout] fp32 -> bf16 MFMA-B fragments with INTERLEAVED
// column mapping: fragment (kt,nt), lane l, elem i <-
//     W[kt*32 + 8*(l>>4) + i][(nt>>1)*32 + 2*(l&15) + (nt&1)]
// Wave w owns tiles {2w,2w+1} -> a lane's two D-cols are adjacent features
// 32w+2*lr{,+1} -> packed b32 LDS writes / float2 global stores downstream.
// ---------------------------------------------------------------------------
__global__ void prep_weights(const float* __restrict__ Wp,
                             const float* __restrict__ W1,
                             const float* __restrict__ W2,
                             unsigned short* __restrict__ wpf,
                             unsigned short* __restrict__ w1f,
                             unsigned short* __restrict__ w2f) {
  int t = blockIdx.x * 256 + threadIdx.x;   // 72*256 = 18432 = 288*64
  int q = t >> 6, l = t & 63;
  const float* W; unsigned short* dst; int NT, Nout, qb;
  if (q < 32)       { W = Wp; dst = wpf; NT = 8;  Nout = 128; qb = q; }
  else if (q < 160) { W = W1; dst = w1f; NT = 32; Nout = 512; qb = q - 32; }
  else              { W = W2; dst = w2f; NT = 8;  Nout = 128; qb = q - 160; }
  int kt = qb / NT, nt = qb % NT;
  int row0 = kt * 32 + 8 * (l >> 4);
  int col  = (nt >> 1) * 32 + 2 * (l & 15) + (nt & 1);   // interleaved
  unsigned short v[8];
#pragma unroll
  for (int i = 0; i < 8; ++i) v[i] = f2bf(W[(row0 + i) * Nout + col]);
  uint4 pack;
  pack.x = (unsigned)v[0] | ((unsigned)v[1] << 16);
  pack.y = (unsigned)v[2] | ((unsigned)v[3] << 16);
  pack.z = (unsigned)v[4] | ((unsigned)v[5] << 16);
  pack.w = (unsigned)v[6] | ((unsigned)v[7] << 16);
  *(uint4*)(dst + (size_t)(qb * 64 + l) * 8) = pack;
}

// ---------------------------------------------------------------------------
// Fused kernel (R10 = R6 structure, register demand engineered for (256,3)):
//  - GEMM1 in two halves of 3 m-tiles (acc1 48->24)
//  - P0 in two passes (transient 48->24)
//  - NO cfrag hoist, NO gemm2-ahead pipeline (R7's 64-reg spill cause);
//    between barriers each wave runs gemm3(ch-1)+gemm2(ch)+epi(ch) -- mixed
//    LDS/global/VALU work that waves skew across, replacing the pipeline.
// LDS = 32768 B, SW-swizzled, 256B pitch:
//   [0,24576): x bf16 [96 rows'=3n+d][128]    (dead after GEMM1)
//     overlay: h1 buf0 @0 | h1 buf1 @8192 | h2 @16384
//   [24576,32768): c bf16 [32][128]           (never overwritten)
// Schedule: P0 | bar | GEMM1 | { gemm2(ch); [ch==0: bar]; epi->buf[ch&1];
//   bar; gemm3(ch) }x4 | h2 | bar | out.   7 barriers.
// ---------------------------------------------------------------------------
__global__ __launch_bounds__(256, 3) void fused_kernel(
    const float* __restrict__ x,
    const float* __restrict__ b1,
    const float* __restrict__ b2,
    const unsigned short* __restrict__ wpf,
    const unsigned short* __restrict__ w1f,
    const unsigned short* __restrict__ w2f,
    float* __restrict__ out) {
  __shared__ __align__(16) char smem[32768];
  const int t = threadIdx.x;
  const int l = t & 63;
  const int w = t >> 6;        // wave id (uniform per wave)
  const int lr = l & 15;
  const int lq = l >> 4;
  const long n0 = (long)blockIdx.x * TILE;

  // ---- P0: stage x -> bf16 LDS; c = sum_d x^2 in fp32 from un-rounded x.
  // Two passes of 2 k-chunks -> only 6 float4 live at once.
#pragma unroll
  for (int half = 0; half < 2; ++half) {
    float4 v[2][3];
#pragma unroll
    for (int k = 0; k < 2; ++k) {
      int p = t + (half * 2 + k) * 256, r = p >> 5, f = (p & 31) * 4;
      const float* xp = x + (n0 + r) * 384 + f;
      v[k][0] = *(const float4*)(xp);
      v[k][1] = *(const float4*)(xp + 128);
      v[k][2] = *(const float4*)(xp + 256);
    }
#pragma unroll
    for (int k = 0; k < 2; ++k) {
      int p = t + (half * 2 + k) * 256, r = p >> 5, f = (p & 31) * 4;
      float4 a = v[k][0], b = v[k][1], c = v[k][2];
      uint2 s0 = { pk2(a.x, a.y), pk2(a.z, a.w) };
      uint2 s1 = { pk2(b.x, b.y), pk2(b.z, b.w) };
      uint2 s2 = { pk2(c.x, c.y), pk2(c.z, c.w) };
      uint2 sc = { pk2(a.x*a.x + b.x*b.x + c.x*c.x,
                       a.y*a.y + b.y*b.y + c.y*c.y),
                   pk2(a.z*a.z + b.z*b.z + c.z*c.z,
                       a.w*a.w + b.w*b.w + c.w*c.w) };
      *(uint2*)(smem + SW((3 * r + 0) * 256 + f * 2)) = s0;
      *(uint2*)(smem + SW((3 * r + 1) * 256 + f * 2)) = s1;
      *(uint2*)(smem + SW((3 * r + 2) * 256 + f * 2)) = s2;
      *(uint2*)(smem + SW(24576 + r * 256 + f * 2))   = sc;
    }
  }
  __syncthreads();   // (1) x + c visible

  // ---- GEMM1: linx[r'][g], 96x128, two halves of 3 m-tiles (acc1 24 regs).
  // Wave w owns interleaved cols {32w+2*lr, 32w+2*lr+1} via tiles {2w,2w+1}.
  unsigned lx[6][4];
#pragma unroll
  for (int half = 0; half < 2; ++half) {
    f32x4 acc1[3][2] = {};
#pragma unroll
    for (int kt = 0; kt < 4; ++kt) {
      bf16x8 a[3];
#pragma unroll
      for (int m = 0; m < 3; ++m)
        a[m] = *(const bf16x8*)(smem + SW(((half * 3 + m) * 16 + lr) * 256 + kt * 64 + lq * 16));
#pragma unroll
      for (int jj = 0; jj < 2; ++jj) {
        bf16x8 b = *(const bf16x8*)(wpf + (size_t)((kt * 8 + 2 * w + jj) * 64 + l) * 8);
#pragma unroll
        for (int m = 0; m < 3; ++m) acc1[m][jj] = mfma16(a[m], b, acc1[m][jj]);
      }
    }
#pragma unroll
    for (int m = 0; m < 3; ++m)
#pragma unroll
      for (int reg = 0; reg < 4; ++reg)
        lx[half * 3 + m][reg] = pk2(acc1[m][0][reg], acc1[m][1][reg]);
  }

  // ---- MLP, K-chunked (128 mids/chunk), h1 dbuf @0/@8192, no pipeline.
  f32x4 acc3[2][2] = {};
#pragma unroll
  for (int ch = 0; ch < 4; ++ch) {
    // gemm2(ch): reads stable c region + W1 frags only (no LDS hazard)
    f32x4 acc2[2][2] = {};
#pragma unroll
    for (int kt = 0; kt < 4; ++kt) {
      bf16x8 a2[2];
#pragma unroll
      for (int mt = 0; mt < 2; ++mt)
        a2[mt] = *(const bf16x8*)(smem + SW(24576 + (mt * 16 + lr) * 256 + kt * 64 + lq * 16));
#pragma unroll
      for (int jj = 0; jj < 2; ++jj) {
        bf16x8 b = *(const bf16x8*)(w1f + (size_t)((kt * 32 + ch * 8 + 2 * w + jj) * 64 + l) * 8);
#pragma unroll
        for (int mt = 0; mt < 2; ++mt) acc2[mt][jj] = mfma16(a2[mt], b, acc2[mt][jj]);
      }
    }
    if (ch == 0) __syncthreads();   // (2) GEMM1's x reads done; buf0 writable
    // epilogue(ch): bias + tanh -> packed b32 into buf[ch&1]
    {
      const int bufb = (ch & 1) * 8192;
      float2 b1v = *(const float2*)(b1 + ch * 128 + w * 32 + 2 * lr);
#pragma unroll
      for (int mt = 0; mt < 2; ++mt)
#pragma unroll
        for (int reg = 0; reg < 4; ++reg) {
          int row = mt * 16 + 4 * lq + reg;
          unsigned pk = pk2(fast_tanh(acc2[mt][0][reg] + b1v.x),
                            fast_tanh(acc2[mt][1][reg] + b1v.y));
          *(unsigned*)(smem + SW(bufb + row * 256 + w * 64 + 4 * lr)) = pk;
        }
    }
    __syncthreads();   // (3..6) h1 chunk visible
    // gemm3(ch): acc3 += h1c @ W2[K-slice,:]
    {
      const int bufb = (ch & 1) * 8192;
#pragma unroll
      for (int kt = 0; kt < 4; ++kt) {
        bf16x8 a3[2];
#pragma unroll
        for (int mt = 0; mt < 2; ++mt)
          a3[mt] = *(const bf16x8*)(smem + SW(bufb + (mt * 16 + lr) * 256 + kt * 64 + lq * 16));
#pragma unroll
        for (int jj = 0; jj < 2; ++jj) {
          bf16x8 b = *(const bf16x8*)(w2f + (size_t)(((ch * 4 + kt) * 8 + 2 * w + jj) * 64 + l) * 8);
#pragma unroll
          for (int mt = 0; mt < 2; ++mt) acc3[mt][jj] = mfma16(a3[mt], b, acc3[mt][jj]);
        }
      }
    }
  }

  // ---- h2 = acc3 + b2 -> bf16 pairs @16384 (x rows 64..95: long dead)
  {
    float2 b2v = *(const float2*)(b2 + w * 32 + 2 * lr);
#pragma unroll
    for (int mt = 0; mt < 2; ++mt)
#pragma unroll
      for (int reg = 0; reg < 4; ++reg) {
        int row = mt * 16 + 4 * lq + reg;
        *(unsigned*)(smem + SW(16384 + row * 256 + w * 64 + 4 * lr)) =
            pk2(acc3[mt][0][reg] + b2v.x, acc3[mt][1][reg] + b2v.y);
      }
  }
  __syncthreads();   // (7) h2 visible

  // ---- Final: out[n,d,g] = linx * h2, float2 stores (128B segments/quad)
#pragma unroll
  for (int mt = 0; mt < 6; ++mt)
#pragma unroll
    for (int reg = 0; reg < 4; ++reg) {
      int rp = mt * 16 + 4 * lq + reg;
      int n = rp / 3;   // magic-mul
      unsigned hp = *(const unsigned*)(smem + SW(16384 + n * 256 + w * 64 + 4 * lr));
      unsigned pk = lx[mt][reg];
      float2 o = { bflo(pk) * bflo(hp), bfhi(pk) * bfhi(hp) };
      *(float2*)(out + n0 * 384 + (long)rp * 128 + w * 32 + 2 * lr) = o;
    }
}

extern "C" void kernel_launch(void* const* d_in, const int* in_sizes, int n_in,
                              void* d_out, int out_size, void* d_ws, size_t ws_size,
                              hipStream_t stream) {
  const float* x  = (const float*)d_in[0];
  const float* Wp = (const float*)d_in[1];
  const float* W1 = (const float*)d_in[2];
  const float* b1 = (const float*)d_in[3];
  const float* W2 = (const float*)d_in[4];
  const float* b2 = (const float*)d_in[5];
  float* out = (float*)d_out;

  // ws layout: W1f [128KB] | W2f [128KB] | Wpf [32KB]
  if (ws_size < 294912) return;
  unsigned short* w1f = (unsigned short*)d_ws;
  unsigned short* w2f = (unsigned short*)((char*)d_ws + 131072);
  unsigned short* wpf = (unsigned short*)((char*)d_ws + 262144);

  prep_weights<<<72, 256, 0, stream>>>(Wp, W1, W2, wpf, w1f, w2f);
  fused_kernel<<<NBLOCKS, 256, 0, stream>>>(x, b1, b2, wpf, w1f, w2f, out);
}